// Round 15
// baseline (569.441 us; speedup 1.0000x reference)
//
#include <hip/hip_runtime.h>
#include <hip/hip_bf16.h>

#define HH 128
#define LAYERS 6
#define EPS_LN 1e-5f
#define NN 40000
#define EE 120000

typedef short vs8  __attribute__((ext_vector_type(8)));
typedef float f32x4 __attribute__((ext_vector_type(4)));

__device__ __forceinline__ short f2b(float f){ __hip_bfloat16 h=__float2bfloat16(f); short s; __builtin_memcpy(&s,&h,2); return s; }
__device__ __forceinline__ float b2f(short s){ __hip_bfloat16 h; __builtin_memcpy(&h,&s,2); return __bfloat162float(h); }
__device__ __forceinline__ float cvf(const void* p, size_t i, int f32){
    return f32 ? ((const float*)p)[i] : __bfloat162float(((const __hip_bfloat16*)p)[i]);
}

// cooperative copy of one 8 KB weight slice (512 int4), 256 threads
__device__ __forceinline__ void stage8K(short* dst, const short* src, int tid){
    ((int4*)dst)[tid]       = ((const int4*)src)[tid];
    ((int4*)dst)[tid + 256] = ((const int4*)src)[tid + 256];
}

struct PtrTab { const void* p[35]; };

// f32 vector-workspace offsets (floats)
#define VO_EN_B1 0
#define VO_EN_B2 128
#define VO_EN_G  256
#define VO_EN_B  384
#define VO_EE_B1 512
#define VO_EE_B2 640
#define VO_EE_G  768
#define VO_EE_B  896
#define VO_PE_B1 1024
#define VO_PE_B2 1792
#define VO_PE_G  2560
#define VO_PE_B  3328
#define VO_PN_B1 4096
#define VO_PN_B2 4864
#define VO_PN_G  5632
#define VO_PN_B  6400
#define VO_DEC_B1 7168
#define VO_DEC_B2 7296
#define VO_DEC_W2 7424
#define VO_MEAN_X 7808
#define VO_STD_X  7824
#define VO_MEAN_E 7840
#define VO_STD_E  7856
#define VO_EN_W1  7872
#define VO_EE_W1  9280

// ---------------------------------------------------------------------------
// Prep kernels
// ---------------------------------------------------------------------------
__global__ void detect_kernel(PtrTab P, int* __restrict__ flags)
{
    if (threadIdx.x == 0 && blockIdx.x == 0) {
        flags[0] = (((const unsigned*)P.p[4])[0] == 0x3F800000u) ? 1 : 0;   // std_x==1.0f
        const unsigned* e = (const unsigned*)P.p[2];
        unsigned acc = 0;
        for (int k = 0; k < 32; ++k) acc |= e[2 * k + 1];
        flags[1] = (acc == 0u) ? 1 : 0;                                      // int64 indices
    }
}

__device__ void cpv(float* vws, int off, const void* src, int n, int f, int t)
{
    for (int i = t; i < n; i += 256) vws[off + i] = cvf(src, i, f);
}

// fused: pack_vecs (block 0) + pack_idx + histogram
__global__ void prep_misc(PtrTab P, float* __restrict__ vws,
                          int* __restrict__ srcv, int* __restrict__ dstv,
                          int* __restrict__ cnt, const int* __restrict__ flags)
{
    const int t = threadIdx.x, f = flags[0];
    if (blockIdx.x == 0) {
        cpv(vws, VO_EN_B1, P.p[8],  128, f, t);  cpv(vws, VO_EN_B2, P.p[10], 128, f, t);
        cpv(vws, VO_EN_G,  P.p[11], 128, f, t);  cpv(vws, VO_EN_B,  P.p[12], 128, f, t);
        cpv(vws, VO_EE_B1, P.p[14], 128, f, t);  cpv(vws, VO_EE_B2, P.p[16], 128, f, t);
        cpv(vws, VO_EE_G,  P.p[17], 128, f, t);  cpv(vws, VO_EE_B,  P.p[18], 128, f, t);
        cpv(vws, VO_PE_B1, P.p[26], 768, f, t);  cpv(vws, VO_PE_B2, P.p[28], 768, f, t);
        cpv(vws, VO_PE_G,  P.p[29], 768, f, t);  cpv(vws, VO_PE_B,  P.p[30], 768, f, t);
        cpv(vws, VO_PN_B1, P.p[20], 768, f, t);  cpv(vws, VO_PN_B2, P.p[22], 768, f, t);
        cpv(vws, VO_PN_G,  P.p[23], 768, f, t);  cpv(vws, VO_PN_B,  P.p[24], 768, f, t);
        cpv(vws, VO_DEC_B1, P.p[32], 128, f, t); cpv(vws, VO_DEC_B2, P.p[34], 3, f, t);
        cpv(vws, VO_DEC_W2, P.p[33], 384, f, t);
        cpv(vws, VO_MEAN_X, P.p[3], 11, f, t);   cpv(vws, VO_STD_X, P.p[4], 11, f, t);
        cpv(vws, VO_MEAN_E, P.p[5], 3, f, t);    cpv(vws, VO_STD_E, P.p[6], 3, f, t);
        cpv(vws, VO_EN_W1, P.p[7], 11 * 128, f, t);
        cpv(vws, VO_EE_W1, P.p[13], 3 * 128, f, t);
    }
    const int e = blockIdx.x * 256 + t;
    if (e < EE) {
        int s, d;
        if (flags[1]) {
            const long long* p = (const long long*)P.p[2];
            s = (int)p[e]; d = (int)p[(size_t)EE + e];
        } else {
            const int* p = (const int*)P.p[2];
            s = p[e]; d = p[EE + e];
        }
        srcv[e] = s; dstv[e] = d;
        atomicAdd(&cnt[s], 1);
    }
}

// all weight repacks in one kernel
// packed[((kk*8 + ct)*64 + lane)*8 + j] = W[mat; kk*32 + (lane>>4)*8 + j; ct*16 + (lane&15)]
struct WDesc { const void* src; short* dst; int K; int base; int size; };
struct WTab  { WDesc d[7]; };

__global__ void pack_w_all(WTab T, const int* __restrict__ flags)
{
    const int id = blockIdx.x * 256 + threadIdx.x;
    int s = -1;
    #pragma unroll
    for (int k = 0; k < 7; ++k)
        if (id >= T.d[k].base && id < T.d[k].base + T.d[k].size) s = k;
    if (s < 0) return;
    const int K = T.d[s].K, nk = K >> 5;
    const int local = id - T.d[s].base;
    const int lane = local & 63;
    const int r    = local >> 6;
    const int ct   = r & 7;
    const int r2   = r >> 3;
    const int kk   = r2 % nk;
    const int m    = r2 / nk;
    const int f    = flags[0];
    const size_t so = (size_t)m * K * HH + ((size_t)(kk * 32 + (lane >> 4) * 8)) * HH
                    + ct * 16 + (lane & 15);
    const size_t dof = (size_t)local * 8;
    #pragma unroll
    for (int j = 0; j < 8; ++j)
        T.d[s].dst[dof + j] = f2b(cvf(T.d[s].src, so + (size_t)j * HH, f));
}

// ---------------------------------------------------------------------------
// CSR scans + edge sort (by src): srcs/dsts are the PERMUTED index arrays,
// ea is stored in sorted order throughout.
// ---------------------------------------------------------------------------
__global__ void scan_block(const int* __restrict__ cnt, int* __restrict__ startv,
                           int* __restrict__ bsum, int N)
{
    __shared__ int sh[256];
    const int b = blockIdx.x, t = threadIdx.x, n = b * 256 + t;
    int v = (n < N) ? cnt[n] : 0;
    sh[t] = v; __syncthreads();
    for (int o = 1; o < 256; o <<= 1) {
        int x = (t >= o) ? sh[t - o] : 0; __syncthreads();
        sh[t] += x; __syncthreads();
    }
    if (n < N) startv[n] = sh[t] - v;
    if (t == 255) bsum[b] = sh[t];
}

__global__ void scan_top(int* __restrict__ bsum, int NB)
{
    __shared__ int sh[256];
    const int t = threadIdx.x;
    int v = (t < NB) ? bsum[t] : 0;
    sh[t] = v; __syncthreads();
    for (int o = 1; o < 256; o <<= 1) {
        int x = (t >= o) ? sh[t - o] : 0; __syncthreads();
        sh[t] += x; __syncthreads();
    }
    if (t < NB) bsum[t] = sh[t] - v;
}

__global__ void scan_add(int* __restrict__ startv, const int* __restrict__ bsum,
                         int* __restrict__ cursor, int N)
{
    const int n = blockIdx.x * 256 + threadIdx.x;
    if (n >= N) return;
    const int s = startv[n] + bsum[n >> 8];
    startv[n] = s; cursor[n] = s;
}

__global__ void scatter_kernel(const int* __restrict__ srcv, const int* __restrict__ dstv,
                               int* __restrict__ cursor, int* __restrict__ eorder,
                               int* __restrict__ srcs, int* __restrict__ dsts, int E)
{
    const int e = blockIdx.x * 256 + threadIdx.x;
    if (e >= E) return;
    const int s = srcv[e];
    const int p = atomicAdd(&cursor[s], 1);
    eorder[p] = e;
    srcs[p] = s;
    dsts[p] = dstv[e];
}

// ---------------------------------------------------------------------------
// Edge layer: m = LN(MLP(cat[x[dst],x[src],ea])) + ea ; ea <- m   (sorted order)
// 64 edges/block, 4 waves x 16 rows. Weights LDS-staged in 8KB slices
// (16KB dbuf). Epilogue: LN (C-layout) -> in-place residual add (A-layout)
// in H_s -> barrier -> full-line cooperative int4 store.
// LDS = 16K wbuf + 17K H_s = 33.8 KB -> 4 blocks/CU = 16 waves.
// ---------------------------------------------------------------------------
__launch_bounds__(256, 4)
__global__ void edge_mfma(const short* __restrict__ x, short* __restrict__ ea,
                          const int* __restrict__ srcs, const int* __restrict__ dsts,
                          const short* __restrict__ w1p, const short* __restrict__ w2p,
                          const float* __restrict__ bias1, const float* __restrict__ bias2,
                          const float* __restrict__ gammaf, const float* __restrict__ betaf)
{
    const int tid = threadIdx.x, wave = tid >> 6, lane = tid & 63;
    const int q = lane >> 4, lm = lane & 15;
    const int e0 = blockIdx.x * 64;
    const int myrow = e0 + wave * 16 + lm;
    __shared__ __align__(16) short wbuf[2][4096];
    __shared__ __align__(16) short H_s[64][136];

    const short* xd = x + (size_t)dsts[myrow] * HH;
    const short* xs = x + (size_t)srcs[myrow] * HH;   // nearly-sequential (sorted)
    const short* er = ea + (size_t)myrow * HH;        // contiguous rows

    vs8 afr[12];
    #pragma unroll
    for (int kk = 0; kk < 4; ++kk) {
        afr[kk]     = *(const vs8*)(xd + kk * 32 + q * 8);
        afr[4 + kk] = *(const vs8*)(xs + kk * 32 + q * 8);
        afr[8 + kk] = *(const vs8*)(er + kk * 32 + q * 8);
    }

    stage8K(wbuf[0], w1p, tid);            // slice 0
    __syncthreads();

    f32x4 acc[8];
    #pragma unroll
    for (int c = 0; c < 8; ++c) acc[c] = (f32x4)0.f;

    #pragma unroll
    for (int kk = 0; kk < 12; ++kk) {      // 12 slices of w1
        const int p = kk & 1;
        if (kk < 11) stage8K(wbuf[1 - p], w1p + (size_t)(kk + 1) * 4096, tid);
        else         stage8K(wbuf[1 - p], w2p, tid);        // w2 slice 0
        #pragma unroll
        for (int c = 0; c < 8; ++c) {
            vs8 b = *(const vs8*)&wbuf[p][(c * 64 + lane) * 8];
            acc[c] = __builtin_amdgcn_mfma_f32_16x16x32_bf16(afr[kk], b, acc[c], 0, 0, 0);
        }
        __syncthreads();
    }

    float b1v[8], b2v[8], gv[8], bv[8];
    #pragma unroll
    for (int c = 0; c < 8; ++c) {
        const int col = c * 16 + lm;
        b1v[c] = bias1[col]; b2v[c] = bias2[col]; gv[c] = gammaf[col]; bv[c] = betaf[col];
    }

    #pragma unroll
    for (int c = 0; c < 8; ++c) {
        const int col = c * 16 + lm;
        #pragma unroll
        for (int reg = 0; reg < 4; ++reg)
            H_s[wave * 16 + q * 4 + reg][col] = f2b(fmaxf(acc[c][reg] + b1v[c], 0.f));
    }
    // wave-private rows: no barrier

    f32x4 acc2[8];
    #pragma unroll
    for (int c = 0; c < 8; ++c) acc2[c] = (f32x4)0.f;
    #pragma unroll
    for (int j = 0; j < 4; ++j) {          // 4 slices of w2; slice0 in wbuf[0]
        const int p = j & 1;
        if (j < 3) stage8K(wbuf[1 - p], w2p + (size_t)(j + 1) * 4096, tid);
        vs8 a = *(const vs8*)&H_s[wave * 16 + lm][j * 32 + q * 8];
        #pragma unroll
        for (int c = 0; c < 8; ++c) {
            vs8 b = *(const vs8*)&wbuf[p][(c * 64 + lane) * 8];
            acc2[c] = __builtin_amdgcn_mfma_f32_16x16x32_bf16(a, b, acc2[c], 0, 0, 0);
        }
        if (j < 3) __syncthreads();
    }

    // LayerNorm in C-layout, write normalized values to H_s
    #pragma unroll
    for (int reg = 0; reg < 4; ++reg) {
        float vv[8], s = 0.f, s2 = 0.f;
        #pragma unroll
        for (int c = 0; c < 8; ++c) {
            float v = acc2[c][reg] + b2v[c];
            vv[c] = v; s += v; s2 += v * v;
        }
        #pragma unroll
        for (int off = 1; off < 16; off <<= 1) { s += __shfl_xor(s, off); s2 += __shfl_xor(s2, off); }
        const float mu = s * (1.f / 128.f);
        const float rs = rsqrtf(s2 * (1.f / 128.f) - mu * mu + EPS_LN);
        #pragma unroll
        for (int c = 0; c < 8; ++c)
            H_s[wave * 16 + q * 4 + reg][c * 16 + lm] = f2b((vv[c] - mu) * rs * gv[c] + bv[c]);
    }

    // in-place residual add in A-layout (wave-synchronous), then coalesced store
    #pragma unroll
    for (int kk = 0; kk < 4; ++kk) {
        vs8 nv = *(const vs8*)&H_s[wave * 16 + lm][kk * 32 + q * 8];
        union { vs8 v; short el[8]; } u;
        #pragma unroll
        for (int j = 0; j < 8; ++j)
            u.el[j] = f2b(b2f(nv[j]) + b2f(afr[8 + kk][j]));
        *(vs8*)&H_s[wave * 16 + lm][kk * 32 + q * 8] = u.v;
    }
    __syncthreads();
    {
        int4* g = (int4*)(ea + (size_t)e0 * HH);
        #pragma unroll
        for (int it = 0; it < 4; ++it) {
            const int i = tid + it * 256;           // 1024 int4, full lines
            g[i] = *(const int4*)&H_s[i >> 4][(i & 15) * 8];
        }
    }
}

// ---------------------------------------------------------------------------
// Node layer: x = x + LN(MLP(cat[x, agg])) ; agg = contiguous CSR range sum.
// Same 8KB-slice staging + coalesced epilogue as edge. LDS 33.8 KB -> 4 blk/CU.
// ---------------------------------------------------------------------------
__launch_bounds__(256, 4)
__global__ void node_mfma(short* __restrict__ x, const short* __restrict__ m,
                          const int* __restrict__ startv, const int* __restrict__ cnt,
                          const short* __restrict__ w1p, const short* __restrict__ w2p,
                          const float* __restrict__ bias1, const float* __restrict__ bias2,
                          const float* __restrict__ gammaf, const float* __restrict__ betaf)
{
    const int tid = threadIdx.x, wave = tid >> 6, lane = tid & 63;
    const int q = lane >> 4, lm = lane & 15;
    const int n0 = blockIdx.x * 64;
    const int myrow = n0 + wave * 16 + lm;
    __shared__ __align__(16) short wbuf[2][4096];
    __shared__ __align__(16) short H_s[64][136];

    const short* xr = x + (size_t)myrow * HH;
    const int s0 = startv[myrow], c0 = cnt[myrow];

    vs8 afr[8];
    #pragma unroll
    for (int kk = 0; kk < 4; ++kk)
        afr[kk] = *(const vs8*)(xr + kk * 32 + q * 8);
    {
        float af[4][8];
        #pragma unroll
        for (int kk = 0; kk < 4; ++kk)
            #pragma unroll
            for (int j = 0; j < 8; ++j) af[kk][j] = 0.f;
        for (int i = 0; i < c0; ++i) {                 // contiguous rows
            const short* mr = m + (size_t)(s0 + i) * HH;
            #pragma unroll
            for (int kk = 0; kk < 4; ++kk) {
                vs8 v = *(const vs8*)(mr + kk * 32 + q * 8);
                #pragma unroll
                for (int j = 0; j < 8; ++j) af[kk][j] += b2f(v[j]);
            }
        }
        #pragma unroll
        for (int kk = 0; kk < 4; ++kk) {
            union { vs8 v; short el[8]; } u;
            #pragma unroll
            for (int j = 0; j < 8; ++j) u.el[j] = f2b(af[kk][j]);
            afr[4 + kk] = u.v;
        }
    }

    stage8K(wbuf[0], w1p, tid);
    __syncthreads();

    f32x4 acc[8];
    #pragma unroll
    for (int c = 0; c < 8; ++c) acc[c] = (f32x4)0.f;

    #pragma unroll
    for (int kk = 0; kk < 8; ++kk) {       // 8 slices of w1
        const int p = kk & 1;
        if (kk < 7) stage8K(wbuf[1 - p], w1p + (size_t)(kk + 1) * 4096, tid);
        else        stage8K(wbuf[1 - p], w2p, tid);
        #pragma unroll
        for (int c = 0; c < 8; ++c) {
            vs8 b = *(const vs8*)&wbuf[p][(c * 64 + lane) * 8];
            acc[c] = __builtin_amdgcn_mfma_f32_16x16x32_bf16(afr[kk], b, acc[c], 0, 0, 0);
        }
        __syncthreads();
    }
    // w2 slice 0 now in wbuf[0]

    float b1v[8], b2v[8], gv[8], bv[8];
    #pragma unroll
    for (int c = 0; c < 8; ++c) {
        const int col = c * 16 + lm;
        b1v[c] = bias1[col]; b2v[c] = bias2[col]; gv[c] = gammaf[col]; bv[c] = betaf[col];
    }

    #pragma unroll
    for (int c = 0; c < 8; ++c) {
        const int col = c * 16 + lm;
        #pragma unroll
        for (int reg = 0; reg < 4; ++reg)
            H_s[wave * 16 + q * 4 + reg][col] = f2b(fmaxf(acc[c][reg] + b1v[c], 0.f));
    }

    f32x4 acc2[8];
    #pragma unroll
    for (int c = 0; c < 8; ++c) acc2[c] = (f32x4)0.f;
    #pragma unroll
    for (int j = 0; j < 4; ++j) {
        const int p = j & 1;
        if (j < 3) stage8K(wbuf[1 - p], w2p + (size_t)(j + 1) * 4096, tid);
        vs8 a = *(const vs8*)&H_s[wave * 16 + lm][j * 32 + q * 8];
        #pragma unroll
        for (int c = 0; c < 8; ++c) {
            vs8 b = *(const vs8*)&wbuf[p][(c * 64 + lane) * 8];
            acc2[c] = __builtin_amdgcn_mfma_f32_16x16x32_bf16(a, b, acc2[c], 0, 0, 0);
        }
        if (j < 3) __syncthreads();
    }

    #pragma unroll
    for (int reg = 0; reg < 4; ++reg) {
        float vv[8], s = 0.f, s2 = 0.f;
        #pragma unroll
        for (int c = 0; c < 8; ++c) {
            float v = acc2[c][reg] + b2v[c];
            vv[c] = v; s += v; s2 += v * v;
        }
        #pragma unroll
        for (int off = 1; off < 16; off <<= 1) { s += __shfl_xor(s, off); s2 += __shfl_xor(s2, off); }
        const float mu = s * (1.f / 128.f);
        const float rs = rsqrtf(s2 * (1.f / 128.f) - mu * mu + EPS_LN);
        #pragma unroll
        for (int c = 0; c < 8; ++c)
            H_s[wave * 16 + q * 4 + reg][c * 16 + lm] = f2b((vv[c] - mu) * rs * gv[c] + bv[c]);
    }

    #pragma unroll
    for (int kk = 0; kk < 4; ++kk) {
        vs8 nv = *(const vs8*)&H_s[wave * 16 + lm][kk * 32 + q * 8];
        union { vs8 v; short el[8]; } u;
        #pragma unroll
        for (int j = 0; j < 8; ++j)
            u.el[j] = f2b(b2f(nv[j]) + b2f(afr[kk][j]));   // residual = x
        *(vs8*)&H_s[wave * 16 + lm][kk * 32 + q * 8] = u.v;
    }
    __syncthreads();
    {
        int4* g = (int4*)(x + (size_t)n0 * HH);
        #pragma unroll
        for (int it = 0; it < 4; ++it) {
            const int i = tid + it * 256;
            g[i] = *(const int4*)&H_s[i >> 4][(i & 15) * 8];
        }
    }
}

// ---------------------------------------------------------------------------
// Encoder: LN(relu(xn@w1+b1)@w2+b2), K small (11/3). GEMM2 weights LDS-staged
// in 8KB slices. Optional row permutation (edge encoder -> src-sorted ea).
// ---------------------------------------------------------------------------
template<int K, int KP>
__launch_bounds__(256, 4)
__global__ void enc_mfma(const void* __restrict__ in,
                         const float* __restrict__ meanv, const float* __restrict__ stdv,
                         const float* __restrict__ w1f, const float* __restrict__ bias1,
                         const short* __restrict__ w2p, const float* __restrict__ bias2,
                         const float* __restrict__ gammaf, const float* __restrict__ betaf,
                         short* __restrict__ out, const int* __restrict__ flags,
                         const int* __restrict__ perm)
{
    const int tid = threadIdx.x, wave = tid >> 6, lane = tid & 63;
    const int q = lane >> 4, lm = lane & 15;
    const int r0 = blockIdx.x * 64;
    __shared__ float xn_s[64][KP];
    __shared__ __align__(16) short wbuf[2][4096];
    __shared__ __align__(16) short H_s[64][136];

    const int f = flags[0];
    for (int i = tid; i < 64 * KP; i += 256) {
        const int r = i / KP, k = i % KP;
        if (k < K) {
            const int rr = perm ? perm[r0 + r] : (r0 + r);
            xn_s[r][k] = (cvf(in, (size_t)rr * K + k, f) - meanv[k]) / stdv[k];
        }
    }
    stage8K(wbuf[0], w2p, tid);
    __syncthreads();

    for (int i = tid; i < 64 * HH; i += 256) {
        const int r = i >> 7, c = i & 127;
        float a = bias1[c];
        #pragma unroll
        for (int k = 0; k < K; ++k) a += xn_s[r][k] * w1f[k * HH + c];
        H_s[r][c] = f2b(fmaxf(a, 0.f));
    }
    __syncthreads();

    f32x4 acc2[8];
    #pragma unroll
    for (int c = 0; c < 8; ++c) acc2[c] = (f32x4)0.f;
    #pragma unroll
    for (int j = 0; j < 4; ++j) {
        const int p = j & 1;
        if (j < 3) stage8K(wbuf[1 - p], w2p + (size_t)(j + 1) * 4096, tid);
        vs8 a = *(const vs8*)&H_s[wave * 16 + lm][j * 32 + q * 8];
        #pragma unroll
        for (int c = 0; c < 8; ++c) {
            vs8 b = *(const vs8*)&wbuf[p][(c * 64 + lane) * 8];
            acc2[c] = __builtin_amdgcn_mfma_f32_16x16x32_bf16(a, b, acc2[c], 0, 0, 0);
        }
        __syncthreads();
    }
    float b2v[8], gv[8], bv[8];
    #pragma unroll
    for (int c = 0; c < 8; ++c) {
        const int col = c * 16 + lm;
        b2v[c] = bias2[col]; gv[c] = gammaf[col]; bv[c] = betaf[col];
    }
    #pragma unroll
    for (int reg = 0; reg < 4; ++reg) {
        float vv[8], s = 0.f, s2 = 0.f;
        #pragma unroll
        for (int c = 0; c < 8; ++c) {
            float v = acc2[c][reg] + b2v[c];
            vv[c] = v; s += v; s2 += v * v;
        }
        #pragma unroll
        for (int off = 1; off < 16; off <<= 1) { s += __shfl_xor(s, off); s2 += __shfl_xor(s2, off); }
        const float mu = s * (1.f / 128.f);
        const float rs = rsqrtf(s2 * (1.f / 128.f) - mu * mu + EPS_LN);
        #pragma unroll
        for (int c = 0; c < 8; ++c)
            H_s[wave * 16 + q * 4 + reg][c * 16 + lm] = f2b((vv[c] - mu) * rs * gv[c] + bv[c]);
    }
    __syncthreads();
    {
        int4* g = (int4*)(out + (size_t)r0 * HH);
        #pragma unroll
        for (int it = 0; it < 4; ++it) {
            const int i = tid + it * 256;
            g[i] = *(const int4*)&H_s[i >> 4][(i & 15) * 8];
        }
    }
}

// ---------------------------------------------------------------------------
// Decoder: out = relu(x@w1+b1) @ w2 + b2   -> [N,3]
// ---------------------------------------------------------------------------
__launch_bounds__(256)
__global__ void dec_mfma(const short* __restrict__ x, const short* __restrict__ w1p,
                         const float* __restrict__ bias1, const float* __restrict__ w2f,
                         const float* __restrict__ b2f3, void* __restrict__ out,
                         const int* __restrict__ flags)
{
    const int tid = threadIdx.x, wave = tid >> 6, lane = tid & 63;
    const int q = lane >> 4, lm = lane & 15;
    const int r0 = blockIdx.x * 64;
    const int myrow = r0 + wave * 16 + lm;
    __shared__ __align__(16) short H_s[64][136];

    f32x4 acc[8];
    #pragma unroll
    for (int c = 0; c < 8; ++c) acc[c] = (f32x4)0.f;
    #pragma unroll
    for (int kk = 0; kk < 4; ++kk) {
        vs8 a = *(const vs8*)(x + (size_t)myrow * HH + kk * 32 + q * 8);
        const short* bp = w1p + ((size_t)(kk * 8) * 64 + lane) * 8;
        #pragma unroll
        for (int c = 0; c < 8; ++c) {
            vs8 b = *(const vs8*)(bp + (size_t)c * 64 * 8);
            acc[c] = __builtin_amdgcn_mfma_f32_16x16x32_bf16(a, b, acc[c], 0, 0, 0);
        }
    }
    #pragma unroll
    for (int c = 0; c < 8; ++c) {
        const int col = c * 16 + lm;
        const float bb1 = bias1[col];
        #pragma unroll
        for (int reg = 0; reg < 4; ++reg)
            H_s[wave * 16 + q * 4 + reg][col] = f2b(fmaxf(acc[c][reg] + bb1, 0.f));
    }
    __syncthreads();

    if (tid < 192) {
        const int r = tid / 3, o = tid - 3 * r;
        float a = b2f3[o];
        #pragma unroll 8
        for (int k = 0; k < HH; ++k) a += b2f(H_s[r][k]) * w2f[k * 3 + o];
        const size_t oi = (size_t)(r0 + r) * 3 + o;
        if (flags[0]) ((float*)out)[oi] = a;
        else ((__hip_bfloat16*)out)[oi] = __float2bfloat16(a);
    }
}

// ---------------------------------------------------------------------------
extern "C" void kernel_launch(void* const* d_in, const int* in_sizes, int n_in,
                              void* d_out, int out_size, void* d_ws, size_t ws_size,
                              hipStream_t stream)
{
    char* base = (char*)d_ws;
    size_t off = 0;
    auto alloc = [&](size_t bytes) { void* r = base + off; off = (off + bytes + 255) & ~(size_t)255; return r; };

    int*   flags  = (int*)alloc(256);
    int*   srcv   = (int*)alloc((size_t)EE * 4);
    int*   dstv   = (int*)alloc((size_t)EE * 4);
    int*   srcs   = (int*)alloc((size_t)EE * 4);   // sorted
    int*   dsts   = (int*)alloc((size_t)EE * 4);   // sorted
    short* xb     = (short*)alloc((size_t)NN * HH * 2);
    short* eab    = (short*)alloc((size_t)EE * HH * 2);   // src-sorted order
    float* vws    = (float*)alloc(16384 * 4);
    short* pe_w1p = (short*)alloc((size_t)6 * 384 * HH * 2);
    short* pe_w2p = (short*)alloc((size_t)6 * HH * HH * 2);
    short* pn_w1p = (short*)alloc((size_t)6 * 256 * HH * 2);
    short* pn_w2p = (short*)alloc((size_t)6 * HH * HH * 2);
    short* en_w2p = (short*)alloc((size_t)HH * HH * 2);
    short* ee_w2p = (short*)alloc((size_t)HH * HH * 2);
    short* dc_w1p = (short*)alloc((size_t)HH * HH * 2);
    int*   cnt    = (int*)alloc((size_t)NN * 4);
    int*   startv = (int*)alloc((size_t)NN * 4);
    int*   cursor = (int*)alloc((size_t)NN * 4);
    int*   eorder = (int*)alloc((size_t)EE * 4);
    int*   bsum   = (int*)alloc(1024);

    PtrTab P;
    for (int i = 0; i < 35; ++i) P.p[i] = d_in[i];

    detect_kernel<<<1, 64, 0, stream>>>(P, flags);
    (void)hipMemsetAsync(cnt, 0, (size_t)NN * 4, stream);
    prep_misc<<<(EE + 255) / 256, 256, 0, stream>>>(P, vws, srcv, dstv, cnt, flags);

    WTab T;
    int b = 0;
    auto seg = [&](int i, const void* src, short* dst, int K, int nmat) {
        int sz = nmat * (K / 32) * 512;
        T.d[i] = WDesc{src, dst, K, b, sz};
        b += sz;
    };
    seg(0, d_in[25], pe_w1p, 384, 6);
    seg(1, d_in[27], pe_w2p, 128, 6);
    seg(2, d_in[19], pn_w1p, 256, 6);
    seg(3, d_in[21], pn_w2p, 128, 6);
    seg(4, d_in[9],  en_w2p, 128, 1);
    seg(5, d_in[15], ee_w2p, 128, 1);
    seg(6, d_in[31], dc_w1p, 128, 1);
    pack_w_all<<<(b + 255) / 256, 256, 0, stream>>>(T, flags);

    const int NB = (NN + 255) / 256;   // 157
    scan_block<<<NB, 256, 0, stream>>>(cnt, startv, bsum, NN);
    scan_top<<<1, 256, 0, stream>>>(bsum, NB);
    scan_add<<<NB, 256, 0, stream>>>(startv, bsum, cursor, NN);
    scatter_kernel<<<(EE + 255) / 256, 256, 0, stream>>>(srcv, dstv, cursor,
                                                         eorder, srcs, dsts, EE);

    enc_mfma<11, 16><<<NN / 64, 256, 0, stream>>>(d_in[0],
        vws + VO_MEAN_X, vws + VO_STD_X, vws + VO_EN_W1, vws + VO_EN_B1,
        en_w2p, vws + VO_EN_B2, vws + VO_EN_G, vws + VO_EN_B, xb, flags, nullptr);
    enc_mfma<3, 4><<<EE / 64, 256, 0, stream>>>(d_in[1],
        vws + VO_MEAN_E, vws + VO_STD_E, vws + VO_EE_W1, vws + VO_EE_B1,
        ee_w2p, vws + VO_EE_B2, vws + VO_EE_G, vws + VO_EE_B, eab, flags, eorder);

    for (int l = 0; l < LAYERS; ++l) {
        edge_mfma<<<EE / 64, 256, 0, stream>>>(xb, eab, srcs, dsts,
            pe_w1p + (size_t)l * 384 * HH, pe_w2p + (size_t)l * HH * HH,
            vws + VO_PE_B1 + l * HH, vws + VO_PE_B2 + l * HH,
            vws + VO_PE_G + l * HH, vws + VO_PE_B + l * HH);
        node_mfma<<<NN / 64, 256, 0, stream>>>(xb, eab, startv, cnt,
            pn_w1p + (size_t)l * 256 * HH, pn_w2p + (size_t)l * HH * HH,
            vws + VO_PN_B1 + l * HH, vws + VO_PN_B2 + l * HH,
            vws + VO_PN_G + l * HH, vws + VO_PN_B + l * HH);
    }

    dec_mfma<<<NN / 64, 256, 0, stream>>>(xb, dc_w1p, vws + VO_DEC_B1,
        vws + VO_DEC_W2, vws + VO_DEC_B2, d_out, flags);
}

// Round 16
// 546.173 us; speedup vs baseline: 1.0426x; 1.0426x over previous
//
#include <hip/hip_runtime.h>
#include <hip/hip_bf16.h>

#define HH 128
#define LAYERS 6
#define EPS_LN 1e-5f
#define NN 40000
#define EE 120000
#define ETILES 1875
#define ECHUNK 235      // ceil(1875/8); padded grid 8*235 = 1880
#define NTILES 625
#define NCHUNK 79       // ceil(625/8);  padded grid 8*79  = 632

typedef short vs8  __attribute__((ext_vector_type(8)));
typedef float f32x4 __attribute__((ext_vector_type(4)));

__device__ __forceinline__ short f2b(float f){ __hip_bfloat16 h=__float2bfloat16(f); short s; __builtin_memcpy(&s,&h,2); return s; }
__device__ __forceinline__ float b2f(short s){ __hip_bfloat16 h; __builtin_memcpy(&h,&s,2); return __bfloat162float(h); }
__device__ __forceinline__ float cvf(const void* p, size_t i, int f32){
    return f32 ? ((const float*)p)[i] : __bfloat162float(((const __hip_bfloat16*)p)[i]);
}

// cooperative copy of one 16 KB weight pair (1024 int4), 256 threads
__device__ __forceinline__ void stage32(short* dst, const short* src, int tid){
    #pragma unroll
    for (int i = 0; i < 4; ++i)
        ((int4*)dst)[tid + i * 256] = ((const int4*)src)[tid + i * 256];
}

struct PtrTab { const void* p[35]; };

// f32 vector-workspace offsets (floats)
#define VO_EN_B1 0
#define VO_EN_B2 128
#define VO_EN_G  256
#define VO_EN_B  384
#define VO_EE_B1 512
#define VO_EE_B2 640
#define VO_EE_G  768
#define VO_EE_B  896
#define VO_PE_B1 1024
#define VO_PE_B2 1792
#define VO_PE_G  2560
#define VO_PE_B  3328
#define VO_PN_B1 4096
#define VO_PN_B2 4864
#define VO_PN_G  5632
#define VO_PN_B  6400
#define VO_DEC_B1 7168
#define VO_DEC_B2 7296
#define VO_DEC_W2 7424
#define VO_MEAN_X 7808
#define VO_STD_X  7824
#define VO_MEAN_E 7840
#define VO_STD_E  7856
#define VO_EN_W1  7872
#define VO_EE_W1  9280

// ---------------------------------------------------------------------------
// Prep kernels
// ---------------------------------------------------------------------------
__global__ void detect_kernel(PtrTab P, int* __restrict__ flags)
{
    if (threadIdx.x == 0 && blockIdx.x == 0) {
        flags[0] = (((const unsigned*)P.p[4])[0] == 0x3F800000u) ? 1 : 0;   // std_x==1.0f
        const unsigned* e = (const unsigned*)P.p[2];
        unsigned acc = 0;
        for (int k = 0; k < 32; ++k) acc |= e[2 * k + 1];
        flags[1] = (acc == 0u) ? 1 : 0;                                      // int64 indices
    }
}

__device__ void cpv(float* vws, int off, const void* src, int n, int f, int t)
{
    for (int i = t; i < n; i += 256) vws[off + i] = cvf(src, i, f);
}

// fused: pack_vecs (block 0) + pack_idx + histogram
__global__ void prep_misc(PtrTab P, float* __restrict__ vws,
                          int* __restrict__ srcv, int* __restrict__ dstv,
                          int* __restrict__ cnt, const int* __restrict__ flags)
{
    const int t = threadIdx.x, f = flags[0];
    if (blockIdx.x == 0) {
        cpv(vws, VO_EN_B1, P.p[8],  128, f, t);  cpv(vws, VO_EN_B2, P.p[10], 128, f, t);
        cpv(vws, VO_EN_G,  P.p[11], 128, f, t);  cpv(vws, VO_EN_B,  P.p[12], 128, f, t);
        cpv(vws, VO_EE_B1, P.p[14], 128, f, t);  cpv(vws, VO_EE_B2, P.p[16], 128, f, t);
        cpv(vws, VO_EE_G,  P.p[17], 128, f, t);  cpv(vws, VO_EE_B,  P.p[18], 128, f, t);
        cpv(vws, VO_PE_B1, P.p[26], 768, f, t);  cpv(vws, VO_PE_B2, P.p[28], 768, f, t);
        cpv(vws, VO_PE_G,  P.p[29], 768, f, t);  cpv(vws, VO_PE_B,  P.p[30], 768, f, t);
        cpv(vws, VO_PN_B1, P.p[20], 768, f, t);  cpv(vws, VO_PN_B2, P.p[22], 768, f, t);
        cpv(vws, VO_PN_G,  P.p[23], 768, f, t);  cpv(vws, VO_PN_B,  P.p[24], 768, f, t);
        cpv(vws, VO_DEC_B1, P.p[32], 128, f, t); cpv(vws, VO_DEC_B2, P.p[34], 3, f, t);
        cpv(vws, VO_DEC_W2, P.p[33], 384, f, t);
        cpv(vws, VO_MEAN_X, P.p[3], 11, f, t);   cpv(vws, VO_STD_X, P.p[4], 11, f, t);
        cpv(vws, VO_MEAN_E, P.p[5], 3, f, t);    cpv(vws, VO_STD_E, P.p[6], 3, f, t);
        cpv(vws, VO_EN_W1, P.p[7], 11 * 128, f, t);
        cpv(vws, VO_EE_W1, P.p[13], 3 * 128, f, t);
    }
    const int e = blockIdx.x * 256 + t;
    if (e < EE) {
        int s, d;
        if (flags[1]) {
            const long long* p = (const long long*)P.p[2];
            s = (int)p[e]; d = (int)p[(size_t)EE + e];
        } else {
            const int* p = (const int*)P.p[2];
            s = p[e]; d = p[EE + e];
        }
        srcv[e] = s; dstv[e] = d;
        atomicAdd(&cnt[s], 1);
    }
}

// all weight repacks in one kernel
// packed[((kk*8 + ct)*64 + lane)*8 + j] = W[mat; kk*32 + (lane>>4)*8 + j; ct*16 + (lane&15)]
struct WDesc { const void* src; short* dst; int K; int base; int size; };
struct WTab  { WDesc d[7]; };

__global__ void pack_w_all(WTab T, const int* __restrict__ flags)
{
    const int id = blockIdx.x * 256 + threadIdx.x;
    int s = -1;
    #pragma unroll
    for (int k = 0; k < 7; ++k)
        if (id >= T.d[k].base && id < T.d[k].base + T.d[k].size) s = k;
    if (s < 0) return;
    const int K = T.d[s].K, nk = K >> 5;
    const int local = id - T.d[s].base;
    const int lane = local & 63;
    const int r    = local >> 6;
    const int ct   = r & 7;
    const int r2   = r >> 3;
    const int kk   = r2 % nk;
    const int m    = r2 / nk;
    const int f    = flags[0];
    const size_t so = (size_t)m * K * HH + ((size_t)(kk * 32 + (lane >> 4) * 8)) * HH
                    + ct * 16 + (lane & 15);
    const size_t dof = (size_t)local * 8;
    #pragma unroll
    for (int j = 0; j < 8; ++j)
        T.d[s].dst[dof + j] = f2b(cvf(T.d[s].src, so + (size_t)j * HH, f));
}

// ---------------------------------------------------------------------------
// CSR scans + edge sort (by src): srcs/dsts are the PERMUTED index arrays,
// ea is stored in sorted order throughout.
// ---------------------------------------------------------------------------
__global__ void scan_block(const int* __restrict__ cnt, int* __restrict__ startv,
                           int* __restrict__ bsum, int N)
{
    __shared__ int sh[256];
    const int b = blockIdx.x, t = threadIdx.x, n = b * 256 + t;
    int v = (n < N) ? cnt[n] : 0;
    sh[t] = v; __syncthreads();
    for (int o = 1; o < 256; o <<= 1) {
        int x = (t >= o) ? sh[t - o] : 0; __syncthreads();
        sh[t] += x; __syncthreads();
    }
    if (n < N) startv[n] = sh[t] - v;
    if (t == 255) bsum[b] = sh[t];
}

__global__ void scan_top(int* __restrict__ bsum, int NB)
{
    __shared__ int sh[256];
    const int t = threadIdx.x;
    int v = (t < NB) ? bsum[t] : 0;
    sh[t] = v; __syncthreads();
    for (int o = 1; o < 256; o <<= 1) {
        int x = (t >= o) ? sh[t - o] : 0; __syncthreads();
        sh[t] += x; __syncthreads();
    }
    if (t < NB) bsum[t] = sh[t] - v;
}

__global__ void scan_add(int* __restrict__ startv, const int* __restrict__ bsum,
                         int* __restrict__ cursor, int N)
{
    const int n = blockIdx.x * 256 + threadIdx.x;
    if (n >= N) return;
    const int s = startv[n] + bsum[n >> 8];
    startv[n] = s; cursor[n] = s;
}

__global__ void scatter_kernel(const int* __restrict__ srcv, const int* __restrict__ dstv,
                               int* __restrict__ cursor, int* __restrict__ eorder,
                               int* __restrict__ srcs, int* __restrict__ dsts, int E)
{
    const int e = blockIdx.x * 256 + threadIdx.x;
    if (e >= E) return;
    const int s = srcv[e];
    const int p = atomicAdd(&cursor[s], 1);
    eorder[p] = e;
    srcs[p] = s;
    dsts[p] = dstv[e];
}

// ---------------------------------------------------------------------------
// Edge layer: m = LN(MLP(cat[x[dst],x[src],ea])) + ea ; ea <- m   (sorted order)
// R12 structure + XCD-aware tile swizzle: blocks with equal blockIdx%8 (same
// XCD) process a CONTIGUOUS tile range -> per-XCD L2 sees 1/8 of x and a
// contiguous ea slice. Padded grid (1880); out-of-range tiles exit.
// LDS = 32K wbuf + 17K H_s = 49.2 KB -> 3 blocks/CU.
// ---------------------------------------------------------------------------
__launch_bounds__(256, 3)
__global__ void edge_mfma(const short* __restrict__ x, short* __restrict__ ea,
                          const int* __restrict__ srcs, const int* __restrict__ dsts,
                          const short* __restrict__ w1p, const short* __restrict__ w2p,
                          const float* __restrict__ bias1, const float* __restrict__ bias2,
                          const float* __restrict__ gammaf, const float* __restrict__ betaf)
{
    const int bswz = blockIdx.x;
    const int tile = (bswz & 7) * ECHUNK + (bswz >> 3);
    if (tile >= ETILES) return;
    const int tid = threadIdx.x, wave = tid >> 6, lane = tid & 63;
    const int q = lane >> 4, lm = lane & 15;
    const int e0 = tile * 64;
    const int myrow = e0 + wave * 16 + lm;
    __shared__ __align__(16) short wbuf[2][8192];
    __shared__ __align__(16) short H_s[64][136];

    const short* xd = x + (size_t)dsts[myrow] * HH;
    const short* xs = x + (size_t)srcs[myrow] * HH;   // nearly-sequential (sorted)
    const short* er = ea + (size_t)myrow * HH;        // contiguous rows

    vs8 afr[12];
    #pragma unroll
    for (int kk = 0; kk < 4; ++kk) {
        afr[kk]     = *(const vs8*)(xd + kk * 32 + q * 8);
        afr[4 + kk] = *(const vs8*)(xs + kk * 32 + q * 8);
        afr[8 + kk] = *(const vs8*)(er + kk * 32 + q * 8);
    }

    stage32(wbuf[0], w1p, tid);            // pair 0 (slices 0,1)
    __syncthreads();

    f32x4 acc[8];
    #pragma unroll
    for (int c = 0; c < 8; ++c) acc[c] = (f32x4)0.f;

    #pragma unroll
    for (int s = 0; s < 6; ++s) {          // 6 pairs = 12 slices of w1
        const int p = s & 1;
        if (s < 5) stage32(wbuf[1 - p], w1p + (size_t)(s + 1) * 8192, tid);
        else       stage32(wbuf[1 - p], w2p, tid);          // w2 pair 0
        #pragma unroll
        for (int k2 = 0; k2 < 2; ++k2) {
            #pragma unroll
            for (int c = 0; c < 8; ++c) {
                vs8 b = *(const vs8*)&wbuf[p][k2 * 4096 + (c * 64 + lane) * 8];
                acc[c] = __builtin_amdgcn_mfma_f32_16x16x32_bf16(afr[s * 2 + k2], b, acc[c], 0, 0, 0);
            }
        }
        __syncthreads();
    }

    float b1v[8], b2v[8], gv[8], bv[8];
    #pragma unroll
    for (int c = 0; c < 8; ++c) {
        const int col = c * 16 + lm;
        b1v[c] = bias1[col]; b2v[c] = bias2[col]; gv[c] = gammaf[col]; bv[c] = betaf[col];
    }

    #pragma unroll
    for (int c = 0; c < 8; ++c) {
        const int col = c * 16 + lm;
        #pragma unroll
        for (int reg = 0; reg < 4; ++reg)
            H_s[wave * 16 + q * 4 + reg][col] = f2b(fmaxf(acc[c][reg] + b1v[c], 0.f));
    }
    // wave-private rows: no barrier

    f32x4 acc2[8];
    #pragma unroll
    for (int c = 0; c < 8; ++c) acc2[c] = (f32x4)0.f;
    #pragma unroll
    for (int j = 0; j < 2; ++j) {          // 2 pairs = 4 slices of w2
        const int p = j & 1;               // w2 pair 0 is in wbuf[0]
        if (j < 1) stage32(wbuf[1 - p], w2p + 8192, tid);
        #pragma unroll
        for (int k2 = 0; k2 < 2; ++k2) {
            vs8 a = *(const vs8*)&H_s[wave * 16 + lm][(j * 2 + k2) * 32 + q * 8];
            #pragma unroll
            for (int c = 0; c < 8; ++c) {
                vs8 b = *(const vs8*)&wbuf[p][k2 * 4096 + (c * 64 + lane) * 8];
                acc2[c] = __builtin_amdgcn_mfma_f32_16x16x32_bf16(a, b, acc2[c], 0, 0, 0);
            }
        }
        if (j < 1) __syncthreads();
    }

    // LayerNorm in C-layout, write normalized values to H_s
    #pragma unroll
    for (int reg = 0; reg < 4; ++reg) {
        float vv[8], s = 0.f, s2 = 0.f;
        #pragma unroll
        for (int c = 0; c < 8; ++c) {
            float v = acc2[c][reg] + b2v[c];
            vv[c] = v; s += v; s2 += v * v;
        }
        #pragma unroll
        for (int off = 1; off < 16; off <<= 1) { s += __shfl_xor(s, off); s2 += __shfl_xor(s2, off); }
        const float mu = s * (1.f / 128.f);
        const float rs = rsqrtf(s2 * (1.f / 128.f) - mu * mu + EPS_LN);
        #pragma unroll
        for (int c = 0; c < 8; ++c)
            H_s[wave * 16 + q * 4 + reg][c * 16 + lm] = f2b((vv[c] - mu) * rs * gv[c] + bv[c]);
    }

    // in-place residual add in A-layout (wave-synchronous), then coalesced store
    #pragma unroll
    for (int kk = 0; kk < 4; ++kk) {
        vs8 nv = *(const vs8*)&H_s[wave * 16 + lm][kk * 32 + q * 8];
        union { vs8 v; short el[8]; } u;
        #pragma unroll
        for (int j = 0; j < 8; ++j)
            u.el[j] = f2b(b2f(nv[j]) + b2f(afr[8 + kk][j]));
        *(vs8*)&H_s[wave * 16 + lm][kk * 32 + q * 8] = u.v;
    }
    __syncthreads();
    {
        int4* g = (int4*)(ea + (size_t)e0 * HH);
        #pragma unroll
        for (int it = 0; it < 4; ++it) {
            const int i = tid + it * 256;           // 1024 int4, full lines
            g[i] = *(const int4*)&H_s[i >> 4][(i & 15) * 8];
        }
    }
}

// ---------------------------------------------------------------------------
// Node layer: x = x + LN(MLP(cat[x, agg])) ; agg = contiguous CSR range sum.
// R12 structure + XCD-aware tile swizzle (padded grid 632).
// ---------------------------------------------------------------------------
__launch_bounds__(256, 3)
__global__ void node_mfma(short* __restrict__ x, const short* __restrict__ m,
                          const int* __restrict__ startv, const int* __restrict__ cnt,
                          const short* __restrict__ w1p, const short* __restrict__ w2p,
                          const float* __restrict__ bias1, const float* __restrict__ bias2,
                          const float* __restrict__ gammaf, const float* __restrict__ betaf)
{
    const int bswz = blockIdx.x;
    const int tile = (bswz & 7) * NCHUNK + (bswz >> 3);
    if (tile >= NTILES) return;
    const int tid = threadIdx.x, wave = tid >> 6, lane = tid & 63;
    const int q = lane >> 4, lm = lane & 15;
    const int n0 = tile * 64;
    const int myrow = n0 + wave * 16 + lm;
    __shared__ __align__(16) short wbuf[2][8192];
    __shared__ __align__(16) short H_s[64][136];

    const short* xr = x + (size_t)myrow * HH;
    const int s0 = startv[myrow], c0 = cnt[myrow];

    vs8 afr[8];
    #pragma unroll
    for (int kk = 0; kk < 4; ++kk)
        afr[kk] = *(const vs8*)(xr + kk * 32 + q * 8);
    {
        float af[4][8];
        #pragma unroll
        for (int kk = 0; kk < 4; ++kk)
            #pragma unroll
            for (int j = 0; j < 8; ++j) af[kk][j] = 0.f;
        for (int i = 0; i < c0; ++i) {                 // contiguous rows
            const short* mr = m + (size_t)(s0 + i) * HH;
            #pragma unroll
            for (int kk = 0; kk < 4; ++kk) {
                vs8 v = *(const vs8*)(mr + kk * 32 + q * 8);
                #pragma unroll
                for (int j = 0; j < 8; ++j) af[kk][j] += b2f(v[j]);
            }
        }
        #pragma unroll
        for (int kk = 0; kk < 4; ++kk) {
            union { vs8 v; short el[8]; } u;
            #pragma unroll
            for (int j = 0; j < 8; ++j) u.el[j] = f2b(af[kk][j]);
            afr[4 + kk] = u.v;
        }
    }

    stage32(wbuf[0], w1p, tid);
    __syncthreads();

    f32x4 acc[8];
    #pragma unroll
    for (int c = 0; c < 8; ++c) acc[c] = (f32x4)0.f;

    #pragma unroll
    for (int s = 0; s < 4; ++s) {          // 4 pairs = 8 slices of w1
        const int p = s & 1;
        if (s < 3) stage32(wbuf[1 - p], w1p + (size_t)(s + 1) * 8192, tid);
        else       stage32(wbuf[1 - p], w2p, tid);
        #pragma unroll
        for (int k2 = 0; k2 < 2; ++k2) {
            #pragma unroll
            for (int c = 0; c < 8; ++c) {
                vs8 b = *(const vs8*)&wbuf[p][k2 * 4096 + (c * 64 + lane) * 8];
                acc[c] = __builtin_amdgcn_mfma_f32_16x16x32_bf16(afr[s * 2 + k2], b, acc[c], 0, 0, 0);
            }
        }
        __syncthreads();
    }
    // w2 pair 0 now in wbuf[0]

    float b1v[8], b2v[8], gv[8], bv[8];
    #pragma unroll
    for (int c = 0; c < 8; ++c) {
        const int col = c * 16 + lm;
        b1v[c] = bias1[col]; b2v[c] = bias2[col]; gv[c] = gammaf[col]; bv[c] = betaf[col];
    }

    #pragma unroll
    for (int c = 0; c < 8; ++c) {
        const int col = c * 16 + lm;
        #pragma unroll
        for (int reg = 0; reg < 4; ++reg)
            H_s[wave * 16 + q * 4 + reg][col] = f2b(fmaxf(acc[c][reg] + b1v[c], 0.f));
    }

    f32x4 acc2[8];
    #pragma unroll
    for (int c = 0; c < 8; ++c) acc2[c] = (f32x4)0.f;
    #pragma unroll
    for (int j = 0; j < 2; ++j) {
        const int p = j & 1;
        if (j < 1) stage32(wbuf[1 - p], w2p + 8192, tid);
        #pragma unroll
        for (int k2 = 0; k2 < 2; ++k2) {
            vs8 a = *(const vs8*)&H_s[wave * 16 + lm][(j * 2 + k2) * 32 + q * 8];
            #pragma unroll
            for (int c = 0; c < 8; ++c) {
                vs8 b = *(const vs8*)&wbuf[p][k2 * 4096 + (c * 64 + lane) * 8];
                acc2[c] = __builtin_amdgcn_mfma_f32_16x16x32_bf16(a, b, acc2[c], 0, 0, 0);
            }
        }
        if (j < 1) __syncthreads();
    }

    #pragma unroll
    for (int reg = 0; reg < 4; ++reg) {
        float vv[8], s = 0.f, s2 = 0.f;
        #pragma unroll
        for (int c = 0; c < 8; ++c) {
            float v = acc2[c][reg] + b2v[c];
            vv[c] = v; s += v; s2 += v * v;
        }
        #pragma unroll
        for (int off = 1; off < 16; off <<= 1) { s += __shfl_xor(s, off); s2 += __shfl_xor(s2, off); }
        const float mu = s * (1.f / 128.f);
        const float rs = rsqrtf(s2 * (1.f / 128.f) - mu * mu + EPS_LN);
        #pragma unroll
        for (int c = 0; c < 8; ++c)
            H_s[wave * 16 + q * 4 + reg][c * 16 + lm] = f2b((vv[c] - mu) * rs * gv[c] + bv[c]);
    }

    #pragma unroll
    for (int kk = 0; kk < 4; ++kk) {
        vs8 nv = *(const vs8*)&H_s[wave * 16 + lm][kk * 32 + q * 8];
        union { vs8 v; short el[8]; } u;
        #pragma unroll
        for (int j = 0; j < 8; ++j)
            u.el[j] = f2b(b2f(nv[j]) + b2f(afr[kk][j]));   // residual = x
        *(vs8*)&H_s[wave * 16 + lm][kk * 32 + q * 8] = u.v;
    }
    __syncthreads();
    {
        int4* g = (int4*)(x + (size_t)n0 * HH);
        #pragma unroll
        for (int it = 0; it < 4; ++it) {
            const int i = tid + it * 256;
            g[i] = *(const int4*)&H_s[i >> 4][(i & 15) * 8];
        }
    }
}

// ---------------------------------------------------------------------------
// Encoder: LN(relu(xn@w1+b1)@w2+b2), K small (11/3). GEMM2 weights LDS-staged.
// Optional row permutation (edge encoder writes ea in src-sorted order).
// ---------------------------------------------------------------------------
template<int K, int KP>
__launch_bounds__(256, 3)
__global__ void enc_mfma(const void* __restrict__ in,
                         const float* __restrict__ meanv, const float* __restrict__ stdv,
                         const float* __restrict__ w1f, const float* __restrict__ bias1,
                         const short* __restrict__ w2p, const float* __restrict__ bias2,
                         const float* __restrict__ gammaf, const float* __restrict__ betaf,
                         short* __restrict__ out, const int* __restrict__ flags,
                         const int* __restrict__ perm)
{
    const int tid = threadIdx.x, wave = tid >> 6, lane = tid & 63;
    const int q = lane >> 4, lm = lane & 15;
    const int r0 = blockIdx.x * 64;
    __shared__ float xn_s[64][KP];
    __shared__ __align__(16) short wbuf[2][8192];
    __shared__ __align__(16) short H_s[64][136];

    const int f = flags[0];
    for (int i = tid; i < 64 * KP; i += 256) {
        const int r = i / KP, k = i % KP;
        if (k < K) {
            const int rr = perm ? perm[r0 + r] : (r0 + r);
            xn_s[r][k] = (cvf(in, (size_t)rr * K + k, f) - meanv[k]) / stdv[k];
        }
    }
    stage32(wbuf[0], w2p, tid);
    __syncthreads();

    for (int i = tid; i < 64 * HH; i += 256) {
        const int r = i >> 7, c = i & 127;
        float a = bias1[c];
        #pragma unroll
        for (int k = 0; k < K; ++k) a += xn_s[r][k] * w1f[k * HH + c];
        H_s[r][c] = f2b(fmaxf(a, 0.f));
    }
    __syncthreads();

    f32x4 acc2[8];
    #pragma unroll
    for (int c = 0; c < 8; ++c) acc2[c] = (f32x4)0.f;
    #pragma unroll
    for (int j = 0; j < 2; ++j) {
        const int p = j & 1;
        if (j < 1) stage32(wbuf[1 - p], w2p + 8192, tid);
        #pragma unroll
        for (int k2 = 0; k2 < 2; ++k2) {
            vs8 a = *(const vs8*)&H_s[wave * 16 + lm][(j * 2 + k2) * 32 + q * 8];
            #pragma unroll
            for (int c = 0; c < 8; ++c) {
                vs8 b = *(const vs8*)&wbuf[p][k2 * 4096 + (c * 64 + lane) * 8];
                acc2[c] = __builtin_amdgcn_mfma_f32_16x16x32_bf16(a, b, acc2[c], 0, 0, 0);
            }
        }
        if (j < 1) __syncthreads();
    }
    float b2v[8], gv[8], bv[8];
    #pragma unroll
    for (int c = 0; c < 8; ++c) {
        const int col = c * 16 + lm;
        b2v[c] = bias2[col]; gv[c] = gammaf[col]; bv[c] = betaf[col];
    }
    __syncthreads();   // all GEMM2 H_s reads done before LN overwrites
    #pragma unroll
    for (int reg = 0; reg < 4; ++reg) {
        float vv[8], s = 0.f, s2 = 0.f;
        #pragma unroll
        for (int c = 0; c < 8; ++c) {
            float v = acc2[c][reg] + b2v[c];
            vv[c] = v; s += v; s2 += v * v;
        }
        #pragma unroll
        for (int off = 1; off < 16; off <<= 1) { s += __shfl_xor(s, off); s2 += __shfl_xor(s2, off); }
        const float mu = s * (1.f / 128.f);
        const float rs = rsqrtf(s2 * (1.f / 128.f) - mu * mu + EPS_LN);
        #pragma unroll
        for (int c = 0; c < 8; ++c)
            H_s[wave * 16 + q * 4 + reg][c * 16 + lm] = f2b((vv[c] - mu) * rs * gv[c] + bv[c]);
    }
    __syncthreads();
    {
        int4* g = (int4*)(out + (size_t)r0 * HH);
        #pragma unroll
        for (int it = 0; it < 4; ++it) {
            const int i = tid + it * 256;
            g[i] = *(const int4*)&H_s[i >> 4][(i & 15) * 8];
        }
    }
}

// ---------------------------------------------------------------------------
// Decoder: out = relu(x@w1+b1) @ w2 + b2   -> [N,3]
// ---------------------------------------------------------------------------
__launch_bounds__(256)
__global__ void dec_mfma(const short* __restrict__ x, const short* __restrict__ w1p,
                         const float* __restrict__ bias1, const float* __restrict__ w2f,
                         const float* __restrict__ b2f3, void* __restrict__ out,
                         const int* __restrict__ flags)
{
    const int tid = threadIdx.x, wave = tid >> 6, lane = tid & 63;
    const int q = lane >> 4, lm = lane & 15;
    const int r0 = blockIdx.x * 64;
    const int myrow = r0 + wave * 16 + lm;
    __shared__ __align__(16) short H_s[64][136];

    f32x4 acc[8];
    #pragma unroll
    for (int c = 0; c < 8; ++c) acc[c] = (f32x4)0.f;
    #pragma unroll
    for (int kk = 0; kk < 4; ++kk) {
        vs8 a = *(const vs8*)(x + (size_t)myrow * HH + kk * 32 + q * 8);
        const short* bp = w1p + ((size_t)(kk * 8) * 64 + lane) * 8;
        #pragma unroll
        for (int c = 0; c < 8; ++c) {
            vs8 b = *(const vs8*)(bp + (size_t)c * 64 * 8);
            acc[c] = __builtin_amdgcn_mfma_f32_16x16x32_bf16(a, b, acc[c], 0, 0, 0);
        }
    }
    #pragma unroll
    for (int c = 0; c < 8; ++c) {
        const int col = c * 16 + lm;
        const float bb1 = bias1[col];
        #pragma unroll
        for (int reg = 0; reg < 4; ++reg)
            H_s[wave * 16 + q * 4 + reg][col] = f2b(fmaxf(acc[c][reg] + bb1, 0.f));
    }
    __syncthreads();

    if (tid < 192) {
        const int r = tid / 3, o = tid - 3 * r;
        float a = b2f3[o];
        #pragma unroll 8
        for (int k = 0; k < HH; ++k) a += b2f(H_s[r][k]) * w2f[k * 3 + o];
        const size_t oi = (size_t)(r0 + r) * 3 + o;
        if (flags[0]) ((float*)out)[oi] = a;
        else ((__hip_bfloat16*)out)[oi] = __float2bfloat16(a);
    }
}

// ---------------------------------------------------------------------------
extern "C" void kernel_launch(void* const* d_in, const int* in_sizes, int n_in,
                              void* d_out, int out_size, void* d_ws, size_t ws_size,
                              hipStream_t stream)
{
    char* base = (char*)d_ws;
    size_t off = 0;
    auto alloc = [&](size_t bytes) { void* r = base + off; off = (off + bytes + 255) & ~(size_t)255; return r; };

    int*   flags  = (int*)alloc(256);
    int*   srcv   = (int*)alloc((size_t)EE * 4);
    int*   dstv   = (int*)alloc((size_t)EE * 4);
    int*   srcs   = (int*)alloc((size_t)EE * 4);   // sorted
    int*   dsts   = (int*)alloc((size_t)EE * 4);   // sorted
    short* xb     = (short*)alloc((size_t)NN * HH * 2);
    short* eab    = (short*)alloc((size_t)EE * HH * 2);   // src-sorted order
    float* vws    = (float*)alloc(16384 * 4);
    short* pe_w1p = (short*)alloc((size_t)6 * 384 * HH * 2);
    short* pe_w2p = (short*)alloc((size_t)6 * HH * HH * 2);
    short* pn_w1p = (short*)alloc((size_t)6 * 256 * HH * 2);
    short* pn_w2p = (short*)alloc((size_t)6 * HH * HH * 2);
    short* en_w2p = (short*)alloc((size_t)HH * HH * 2);
    short* ee_w2p = (short*)alloc((size_t)HH * HH * 2);
    short* dc_w1p = (short*)alloc((size_t)HH * HH * 2);
    int*   cnt    = (int*)alloc((size_t)NN * 4);
    int*   startv = (int*)alloc((size_t)NN * 4);
    int*   cursor = (int*)alloc((size_t)NN * 4);
    int*   eorder = (int*)alloc((size_t)EE * 4);
    int*   bsum   = (int*)alloc(1024);

    PtrTab P;
    for (int i = 0; i < 35; ++i) P.p[i] = d_in[i];

    detect_kernel<<<1, 64, 0, stream>>>(P, flags);
    (void)hipMemsetAsync(cnt, 0, (size_t)NN * 4, stream);
    prep_misc<<<(EE + 255) / 256, 256, 0, stream>>>(P, vws, srcv, dstv, cnt, flags);

    WTab T;
    int b = 0;
    auto seg = [&](int i, const void* src, short* dst, int K, int nmat) {
        int sz = nmat * (K / 32) * 512;
        T.d[i] = WDesc{src, dst, K, b, sz};
        b += sz;
    };
    seg(0, d_in[25], pe_w1p, 384, 6);
    seg(1, d_in[27], pe_w2p, 128, 6);
    seg(2, d_in[19], pn_w1p, 256, 6);
    seg(3, d_in[21], pn_w2p, 128, 6);
    seg(4, d_in[9],  en_w2p, 128, 1);
    seg(5, d_in[15], ee_w2p, 128, 1);
    seg(6, d_in[31], dc_w1p, 128, 1);
    pack_w_all<<<(b + 255) / 256, 256, 0, stream>>>(T, flags);

    const int NB = (NN + 255) / 256;   // 157
    scan_block<<<NB, 256, 0, stream>>>(cnt, startv, bsum, NN);
    scan_top<<<1, 256, 0, stream>>>(bsum, NB);
    scan_add<<<NB, 256, 0, stream>>>(startv, bsum, cursor, NN);
    scatter_kernel<<<(EE + 255) / 256, 256, 0, stream>>>(srcv, dstv, cursor,
                                                         eorder, srcs, dsts, EE);

    enc_mfma<11, 16><<<NN / 64, 256, 0, stream>>>(d_in[0],
        vws + VO_MEAN_X, vws + VO_STD_X, vws + VO_EN_W1, vws + VO_EN_B1,
        en_w2p, vws + VO_EN_B2, vws + VO_EN_G, vws + VO_EN_B, xb, flags, nullptr);
    enc_mfma<3, 4><<<EE / 64, 256, 0, stream>>>(d_in[1],
        vws + VO_MEAN_E, vws + VO_STD_E, vws + VO_EE_W1, vws + VO_EE_B1,
        ee_w2p, vws + VO_EE_B2, vws + VO_EE_G, vws + VO_EE_B, eab, flags, eorder);

    for (int l = 0; l < LAYERS; ++l) {
        edge_mfma<<<8 * ECHUNK, 256, 0, stream>>>(xb, eab, srcs, dsts,
            pe_w1p + (size_t)l * 384 * HH, pe_w2p + (size_t)l * HH * HH,
            vws + VO_PE_B1 + l * HH, vws + VO_PE_B2 + l * HH,
            vws + VO_PE_G + l * HH, vws + VO_PE_B + l * HH);
        node_mfma<<<8 * NCHUNK, 256, 0, stream>>>(xb, eab, startv, cnt,
            pn_w1p + (size_t)l * 256 * HH, pn_w2p + (size_t)l * HH * HH,
            vws + VO_PN_B1 + l * HH, vws + VO_PN_B2 + l * HH,
            vws + VO_PN_G + l * HH, vws + VO_PN_B + l * HH);
    }

    dec_mfma<<<NN / 64, 256, 0, stream>>>(xb, dc_w1p, vws + VO_DEC_B1,
        vws + VO_DEC_W2, vws + VO_DEC_B2, d_out, flags);
}